// Round 1
// baseline (768.529 us; speedup 1.0000x reference)
//
#include <hip/hip_runtime.h>

#define BATCH 4
#define NPTS 4096
#define NSKEL 100
#define KNN 10

// Kernel 1: per-point KNN-10 (within batch) -> changingrate, fused with
// top-2 point->skeleton distances -> voronoi contribution. One thread per
// query point. Candidate points staged in LDS as float4(x,y,z,|p|^2).
__global__ __launch_bounds__(256) void voronoi_kernel(const float* __restrict__ xyz,
                                                      const float* __restrict__ skel,
                                                      float* __restrict__ out) {
    __shared__ float4 spts[NPTS];  // 64 KB

    const int b    = blockIdx.x >> 4;          // 16 blocks per batch
    const int base = (blockIdx.x & 15) << 8;   // 256 queries per block
    const int tid  = threadIdx.x;

    const float* xb = xyz  + (size_t)b * NPTS * 6;
    const float* sb = skel + (size_t)b * NSKEL * 3;

    // Stage points (x,y,z,|p|^2) into LDS
    for (int i = tid; i < NPTS; i += 256) {
        float x = xb[i * 6 + 0];
        float y = xb[i * 6 + 1];
        float z = xb[i * 6 + 2];
        spts[i] = make_float4(x, y, z, x * x + y * y + z * z);
    }
    __syncthreads();

    const int n = base + tid;
    const float4 q = spts[n];

    // ---- KNN-10 scan over all 4096 candidates (reference d2 formula) ----
    float bd[KNN];
    int   bi[KNN];
#pragma unroll
    for (int k = 0; k < KNN; ++k) { bd[k] = 3.4e38f; bi[k] = 0; }

    for (int j = 0; j < NPTS; ++j) {
        float4 c  = spts[j];
        float dot = q.x * c.x + q.y * c.y + q.z * c.z;
        float d2  = fmaxf(q.w + c.w - 2.0f * dot, 0.0f);
        if (d2 < bd[KNN - 1]) {           // strict < matches top_k tie-break
            bd[KNN - 1] = d2;
            bi[KNN - 1] = j;
#pragma unroll
            for (int k = KNN - 1; k > 0; --k) {
                if (bd[k] < bd[k - 1]) {
                    float td = bd[k]; bd[k] = bd[k - 1]; bd[k - 1] = td;
                    int   ti = bi[k]; bi[k] = bi[k - 1]; bi[k - 1] = ti;
                }
            }
        }
    }

    // ---- changingrate: gather neighbor normals from global (L2-hot) ----
    const float nx = xb[n * 6 + 3];
    const float ny = xb[n * 6 + 4];
    const float nz = xb[n * 6 + 5];
    float cr_sum = 0.0f;
#pragma unroll
    for (int k = 0; k < KNN; ++k) {
        int j = bi[k];
        float mx = xb[j * 6 + 3];
        float my = xb[j * 6 + 4];
        float mz = xb[j * 6 + 5];
        // cross(n, m)
        float cx = ny * mz - nz * my;
        float cy = nz * mx - nx * mz;
        float cz = nx * my - ny * mx;
        float c1 = sqrtf(cx * cx + cy * cy + cz * cz);
        // |n (*) m| elementwise product norm
        float px = nx * mx, py = ny * my, pz = nz * mz;
        float c2 = sqrtf(px * px + py * py + pz * pz);
        cr_sum += fminf(c1, c2);
    }

    // ---- top-2 distances to skeleton points (read from global, uniform
    //      addresses -> scalar loads, L1/L2-hot) ----
    float d0 = 3.4e38f, d1 = 3.4e38f;
    for (int m = 0; m < NSKEL; ++m) {
        float sx = sb[m * 3 + 0];
        float sy = sb[m * 3 + 1];
        float sz = sb[m * 3 + 2];
        float sw = sx * sx + sy * sy + sz * sz;
        float dot = q.x * sx + q.y * sy + q.z * sz;
        float d2  = fmaxf(q.w + sw - 2.0f * dot, 0.0f);
        if (d2 < d0)      { d1 = d0; d0 = d2; }
        else if (d2 < d1) { d1 = d2; }
    }

    float contrib = cr_sum * (d1 - d0);   // |d12[...,0] - d12[...,1]|

    // ---- wave reduce + atomic ----
#pragma unroll
    for (int o = 32; o > 0; o >>= 1) contrib += __shfl_down(contrib, o);
    if ((tid & 63) == 0) atomicAdd(out, contrib);
}

// Kernel 2: skeleton self nearest-neighbor term: -0.5 * sum ||s_m - s_nn2(m)||
__global__ __launch_bounds__(128) void skel_kernel(const float* __restrict__ skel,
                                                   float* __restrict__ out) {
    __shared__ float4 sskl[NSKEL];
    const int b   = blockIdx.x;
    const int tid = threadIdx.x;
    const float* sb = skel + (size_t)b * NSKEL * 3;

    if (tid < NSKEL) {
        float x = sb[tid * 3 + 0];
        float y = sb[tid * 3 + 1];
        float z = sb[tid * 3 + 2];
        sskl[tid] = make_float4(x, y, z, x * x + y * y + z * z);
    }
    __syncthreads();

    float v = 0.0f;
    if (tid < NSKEL) {
        float4 q = sskl[tid];
        float d0 = 3.4e38f, d1 = 3.4e38f;
        int   i0 = 0, i1 = 0;
        for (int j = 0; j < NSKEL; ++j) {
            float4 c  = sskl[j];
            float dot = q.x * c.x + q.y * c.y + q.z * c.z;
            float d2  = fmaxf(q.w + c.w - 2.0f * dot, 0.0f);
            if (d2 < d0)      { d1 = d0; i1 = i0; d0 = d2; i0 = j; }
            else if (d2 < d1) { d1 = d2; i1 = j; }
        }
        float4 c = sskl[i1];                 // knn_skele[..., 1]
        float dx = q.x - c.x, dy = q.y - c.y, dz = q.z - c.z;
        v = sqrtf(dx * dx + dy * dy + dz * dz);
    }
#pragma unroll
    for (int o = 32; o > 0; o >>= 1) v += __shfl_down(v, o);
    if ((tid & 63) == 0) atomicAdd(out, -0.5f * v);
}

extern "C" void kernel_launch(void* const* d_in, const int* in_sizes, int n_in,
                              void* d_out, int out_size, void* d_ws, size_t ws_size,
                              hipStream_t stream) {
    const float* xyz  = (const float*)d_in[0];
    // d_in[1] = num_class (int, == NSKEL) — compile-time constant here
    const float* skel = (const float*)d_in[2];
    float* out = (float*)d_out;

    hipMemsetAsync(out, 0, sizeof(float), stream);
    voronoi_kernel<<<BATCH * (NPTS / 256), 256, 0, stream>>>(xyz, skel, out);
    skel_kernel<<<BATCH, 128, 0, stream>>>(skel, out);
}

// Round 2
// 175.910 us; speedup vs baseline: 4.3689x; 4.3689x over previous
//
#include <hip/hip_runtime.h>

#define BATCH 4
#define NPTS  4096
#define NSKEL 100
#define KNN   10
#define SPLIT 4
#define QPB   64                  // queries per block (256 threads / SPLIT)
#define CHUNK (NPTS / SPLIT)      // 1024 candidates per lane
#define FINF  3.4e38f

// One block = 64 queries x 4 candidate-splits. Each thread scans CHUNK
// candidates keeping a sorted top-10 (score = 0.5|c|^2 - q.c, a monotone
// map of d2), then the 4 lanes of a query merge in-register via the
// bitonic half-cleaner + one transposition sort. Voronoi gap fused.
__global__ __launch_bounds__(256) void voronoi_kernel(const float* __restrict__ xyz,
                                                      const float* __restrict__ skel,
                                                      float* __restrict__ out) {
    __shared__ float4 spts[NPTS];    // x,y,z, 0.5*|p|^2   (64 KB)
    __shared__ float4 sskl[NSKEL];

    const int tid   = threadIdx.x;
    const int b     = blockIdx.x >> 6;
    const int qbase = (blockIdx.x & 63) * QPB;
    const float* xb = xyz  + (size_t)b * NPTS * 6;
    const float* sb = skel + (size_t)b * NSKEL * 3;

    for (int i = tid; i < NPTS; i += 256) {
        float x = xb[i*6+0], y = xb[i*6+1], z = xb[i*6+2];
        spts[i] = make_float4(x, y, z, 0.5f*(x*x + y*y + z*z));
    }
    if (tid < NSKEL) {
        float x = sb[tid*3+0], y = sb[tid*3+1], z = sb[tid*3+2];
        sskl[tid] = make_float4(x, y, z, 0.5f*(x*x + y*y + z*z));
    }
    __syncthreads();

    const int qi    = qbase + (tid >> 2);
    const int split = tid & 3;
    const float4 q  = spts[qi];

    // ---- per-lane top-10 over this split's 1024 candidates ----
    float bs[KNN]; int bix[KNN];
#pragma unroll
    for (int k = 0; k < KNN; ++k) { bs[k] = FINF; bix[k] = 0; }

    const int jb = split * CHUNK;
    for (int t0 = 0; t0 < CHUNK; t0 += 4) {
#pragma unroll
        for (int u = 0; u < 4; ++u) {
            // rotate visit order by `split` so the 4 concurrent broadcast
            // addresses land on different banks (chunks are 16KB apart)
            int jj = (t0 + u + split) & (CHUNK - 1);
            float4 c = spts[jb + jj];
            float s = c.w - (q.x*c.x + q.y*c.y + q.z*c.z);
            if (s < bs[KNN-1]) {
                bs[KNN-1] = s; bix[KNN-1] = jb + jj;
#pragma unroll
                for (int k = KNN-1; k > 0; --k) {
                    if (bs[k] < bs[k-1]) {
                        float tv = bs[k]; bs[k] = bs[k-1]; bs[k-1] = tv;
                        int   ti = bix[k]; bix[k] = bix[k-1]; bix[k-1] = ti;
                    }
                }
            }
        }
    }

    // ---- merge round 1: lane pairs (xor 1), bitonic half-cleaner ----
    {
        float nv[KNN]; int ni[KNN];
#pragma unroll
        for (int i = 0; i < KNN; ++i) {
            float pv = __shfl_xor(bs[KNN-1-i], 1, 64);
            int   pi = __shfl_xor(bix[KNN-1-i], 1, 64);
            bool mine = bs[i] <= pv;
            nv[i] = mine ? bs[i]  : pv;
            ni[i] = mine ? bix[i] : pi;
        }
#pragma unroll
        for (int i = 0; i < KNN; ++i) { bs[i] = nv[i]; bix[i] = ni[i]; }
    }
    // re-sort the merged 10 (odd-even transposition, static indices)
#pragma unroll
    for (int r = 0; r < KNN; ++r) {
#pragma unroll
        for (int k = (r & 1); k + 1 < KNN; k += 2) {
            if (bs[k+1] < bs[k]) {
                float tv = bs[k]; bs[k] = bs[k+1]; bs[k+1] = tv;
                int   ti = bix[k]; bix[k] = bix[k+1]; bix[k+1] = ti;
            }
        }
    }
    // ---- merge round 2: across pairs (xor 2); final set may stay unsorted ----
    {
        float nv[KNN]; int ni[KNN];
#pragma unroll
        for (int i = 0; i < KNN; ++i) {
            float pv = __shfl_xor(bs[KNN-1-i], 2, 64);
            int   pi = __shfl_xor(bix[KNN-1-i], 2, 64);
            bool mine = bs[i] <= pv;
            nv[i] = mine ? bs[i]  : pv;
            ni[i] = mine ? bix[i] : pi;
        }
#pragma unroll
        for (int i = 0; i < KNN; ++i) { bs[i] = nv[i]; bix[i] = ni[i]; }
    }

    // ---- changingrate over the merged top-10 (all 4 lanes hold the set) ----
    const float nx = xb[qi*6+3];
    const float ny = xb[qi*6+4];
    const float nz = xb[qi*6+5];
    float cr = 0.0f;
#pragma unroll
    for (int k = 0; k < KNN; ++k) {
        int j = bix[k];
        float mx = xb[j*6+3], my = xb[j*6+4], mz = xb[j*6+5];
        float cx = ny*mz - nz*my;
        float cy = nz*mx - nx*mz;
        float cz = nx*my - ny*mx;
        float c1 = sqrtf(cx*cx + cy*cy + cz*cz);
        float px = nx*mx, py = ny*my, pz = nz*mz;
        float c2 = sqrtf(px*px + py*py + pz*pz);
        cr += fminf(c1, c2);
    }

    // ---- top-2 skeleton scores, split across the 4 lanes ----
    float t0 = FINF, t1 = FINF;
    for (int m = split; m < NSKEL; m += SPLIT) {
        float4 c = sskl[m];
        float s = c.w - (q.x*c.x + q.y*c.y + q.z*c.z);
        if (s < t0) { t1 = t0; t0 = s; }
        else if (s < t1) { t1 = s; }
    }
#pragma unroll
    for (int m = 1; m <= 2; m <<= 1) {
        float o0 = __shfl_xor(t0, m, 64);
        float o1 = __shfl_xor(t1, m, 64);
        float n0 = fminf(t0, o0);
        float n1 = fminf(fmaxf(t0, o0), fminf(t1, o1));
        t0 = n0; t1 = n1;
    }
    // gap d2_1 - d2_0 == 2*(score_1 - score_0); all 4 lanes duplicate -> 0.25x
    float contrib = 0.25f * cr * 2.0f * (t1 - t0);

#pragma unroll
    for (int o = 32; o > 0; o >>= 1) contrib += __shfl_down(contrib, o);
    if ((tid & 63) == 0) atomicAdd(out, contrib);

    // ---- skeleton self-NN term, one block per batch ----
    if ((blockIdx.x & 63) == 0) {
        float v = 0.0f;
        if (tid < NSKEL) {
            float4 sq = sskl[tid];
            float b0 = FINF, b1 = FINF; int i0 = 0, i1 = 0;
            for (int j = 0; j < NSKEL; ++j) {
                float4 c = sskl[j];
                float s = c.w - (sq.x*c.x + sq.y*c.y + sq.z*c.z);
                if (s < b0)      { b1 = b0; i1 = i0; b0 = s; i0 = j; }
                else if (s < b1) { b1 = s; i1 = j; }
            }
            float4 c = sskl[i1];             // knn_skele[..., 1]
            float dx = sq.x - c.x, dy = sq.y - c.y, dz = sq.z - c.z;
            v = sqrtf(dx*dx + dy*dy + dz*dz);
        }
#pragma unroll
        for (int o = 32; o > 0; o >>= 1) v += __shfl_down(v, o);
        if ((tid & 63) == 0) atomicAdd(out, -0.5f * v);
    }
}

extern "C" void kernel_launch(void* const* d_in, const int* in_sizes, int n_in,
                              void* d_out, int out_size, void* d_ws, size_t ws_size,
                              hipStream_t stream) {
    const float* xyz  = (const float*)d_in[0];
    // d_in[1] = num_class (== NSKEL), compile-time constant here
    const float* skel = (const float*)d_in[2];
    float* out = (float*)d_out;

    hipMemsetAsync(out, 0, sizeof(float), stream);
    voronoi_kernel<<<BATCH * (NPTS / QPB), 256, 0, stream>>>(xyz, skel, out);
}

// Round 3
// 55.172 us; speedup vs baseline: 13.9296x; 3.1884x over previous
//
#include <hip/hip_runtime.h>

#define BATCH  4
#define NPTS   4096
#define NSKEL  100
#define KNN    10
#define SPLIT  16                  // lanes per query-group
#define GROUPS 16                  // thread-groups per 256-block
#define QPB    (GROUPS * 2)        // 32 queries per block (2 per group)
#define CPT    (NPTS / SPLIT)      // 256 candidates per thread
#define BIG    3.0e38f

#if defined(__has_builtin)
#  if __has_builtin(__builtin_amdgcn_fmed3f)
#    define MED3(s,lo,hi) __builtin_amdgcn_fmed3f((s),(lo),(hi))
#  endif
#endif
#ifndef MED3
   // lo <= hi always holds at call sites, so min(max(s,lo),hi) == median
#  define MED3(s,lo,hi) fminf(fmaxf((s),(lo)),(hi))
#endif

#define CE(a,i,j) do { float _lo = fminf(a[i],a[j]); a[j] = fmaxf(a[i],a[j]); a[i] = _lo; } while (0)

// Merge my sorted-ascending 10-list with lane^mask's via bitonic half-cleaner
// (keep 10 smallest), then re-sort with a 15-CE bitonic-10 network (valid for
// the cyclically-bitonic output; derived from BM(16) with -INF front padding).
__device__ __forceinline__ void merge16(float l[KNN], int mask, bool do_sort) {
    float c[KNN];
#pragma unroll
    for (int i = 0; i < KNN; ++i) {
        float o = __shfl_xor(l[KNN - 1 - i], mask, 64);
        c[i] = fminf(l[i], o);
    }
    if (do_sort) {
        CE(c,0,8); CE(c,1,9);
        CE(c,2,6); CE(c,3,7); CE(c,4,8); CE(c,5,9);
        CE(c,2,4); CE(c,3,5); CE(c,6,8); CE(c,7,9); CE(c,0,1);
        CE(c,2,3); CE(c,4,5); CE(c,6,7); CE(c,8,9);
    }
#pragma unroll
    for (int i = 0; i < KNN; ++i) l[i] = c[i];
}

__global__ __launch_bounds__(256, 2) void voronoi_kernel(const float* __restrict__ xyz,
                                                         const float* __restrict__ skel,
                                                         float* __restrict__ out) {
    __shared__ float4 spts[NPTS];    // x,y,z, 0.5*|p|^2   (64 KB)
    __shared__ float4 sskl[NSKEL];
    __shared__ float  part[4];

    const int tid = threadIdx.x;
    const int b   = blockIdx.x >> 7;            // 128 blocks per batch
    const int qb  = (blockIdx.x & 127) * QPB;   // 32 queries per block
    const float* xb = xyz  + (size_t)b * NPTS * 6;
    const float* sb = skel + (size_t)b * NSKEL * 3;

    for (int i = tid; i < NPTS; i += 256) {
        float x = xb[i*6+0], y = xb[i*6+1], z = xb[i*6+2];
        spts[i] = make_float4(x, y, z, 0.5f*(x*x + y*y + z*z));
    }
    if (tid < NSKEL) {
        float x = sb[tid*3+0], y = sb[tid*3+1], z = sb[tid*3+2];
        sskl[tid] = make_float4(x, y, z, 0.5f*(x*x + y*y + z*z));
    }
    __syncthreads();

    const int split = tid & 15;
    const int group = tid >> 4;
    const int q0i = qb + group * 2;
    const float4 Q0 = spts[q0i];
    const float4 Q1 = spts[q0i + 1];

    // ---- branchless packed top-10 scan: score = 0.5|c|^2 - q.c, low 12
    //      mantissa bits replaced by candidate index ----
    float l0[KNN], l1[KNN];
#pragma unroll
    for (int k = 0; k < KNN; ++k) { l0[k] = BIG; l1[k] = BIG; }

    const int jb = split * CPT;
    for (int t = 0; t < CPT; t += 4) {
#pragma unroll
        for (int u = 0; u < 4; ++u) {
            int j = jb + ((t + u + split) & (CPT - 1));   // rotation de-conflicts banks
            float4 c = spts[j];
            float s0 = fmaf(-Q0.x, c.x, fmaf(-Q0.y, c.y, fmaf(-Q0.z, c.z, c.w)));
            float s1 = fmaf(-Q1.x, c.x, fmaf(-Q1.y, c.y, fmaf(-Q1.z, c.z, c.w)));
            float f0 = __uint_as_float((__float_as_uint(s0) & 0xFFFFF000u) | (unsigned)j);
            float f1 = __uint_as_float((__float_as_uint(s1) & 0xFFFFF000u) | (unsigned)j);
#pragma unroll
            for (int k = KNN - 1; k >= 1; --k) l0[k] = MED3(f0, l0[k-1], l0[k]);
            l0[0] = fminf(f0, l0[0]);
#pragma unroll
            for (int k = KNN - 1; k >= 1; --k) l1[k] = MED3(f1, l1[k-1], l1[k]);
            l1[0] = fminf(f1, l1[0]);
        }
    }

    // ---- merge the 16 lanes' lists (final round may stay unsorted) ----
    merge16(l0, 1, true); merge16(l0, 2, true); merge16(l0, 4, true); merge16(l0, 8, false);
    merge16(l1, 1, true); merge16(l1, 2, true); merge16(l1, 4, true); merge16(l1, 8, false);

    // ---- changingrate: even lanes handle q0, odd lanes q1 ----
    const int sel  = split & 1;
    const int myq  = q0i + sel;
    const float4 Q = spts[myq];
    const float nx = xb[myq*6+3], ny = xb[myq*6+4], nz = xb[myq*6+5];
    float ml[KNN];
#pragma unroll
    for (int k = 0; k < KNN; ++k) ml[k] = sel ? l1[k] : l0[k];

    float cr = 0.0f;
#pragma unroll
    for (int k = 0; k < KNN; ++k) {
        int j = (int)(__float_as_uint(ml[k]) & 0xFFFu);
        float mx = xb[j*6+3], my_ = xb[j*6+4], mz = xb[j*6+5];
        float cx = ny*mz - nz*my_;
        float cy = nz*mx - nx*mz;
        float cz = nx*my_ - ny*mx;
        float c1 = sqrtf(cx*cx + cy*cy + cz*cz);
        float px = nx*mx, py = ny*my_, pz = nz*mz;
        float c2 = sqrtf(px*px + py*py + pz*pz);
        cr += fminf(c1, c2);
    }

    // ---- top-2 skeleton scores: 8-way split per query, med3 top-2 ----
    float t0 = BIG, t1 = BIG;
    for (int m = (split >> 1); m < NSKEL; m += 8) {
        float4 c = sskl[m];
        float s = fmaf(-Q.x, c.x, fmaf(-Q.y, c.y, fmaf(-Q.z, c.z, c.w)));
        t1 = MED3(s, t0, t1);      // uses old t0
        t0 = fminf(s, t0);
    }
#pragma unroll
    for (int m = 2; m <= 8; m <<= 1) {
        float o0 = __shfl_xor(t0, m, 64);
        float o1 = __shfl_xor(t1, m, 64);
        float n1 = fminf(fmaxf(t0, o0), fminf(t1, o1));
        t0 = fminf(t0, o0); t1 = n1;
    }
    // d2 gap = 2*(score gap); lanes split<2 are the unique (query) owners
    float contrib = (split < 2) ? cr * 2.0f * (t1 - t0) : 0.0f;

#pragma unroll
    for (int o = 32; o > 0; o >>= 1) contrib += __shfl_down(contrib, o);
    if ((tid & 63) == 0) part[tid >> 6] = contrib;
    __syncthreads();
    if (tid == 0) atomicAdd(out, part[0] + part[1] + part[2] + part[3]);

    // ---- skeleton self-NN term, one block per batch ----
    if ((blockIdx.x & 127) == 0) {
        float v = 0.0f;
        if (tid < NSKEL) {
            float4 sq = sskl[tid];
            float b0 = BIG, b1 = BIG; int i0 = 0, i1 = 0;
            for (int jj = 0; jj < NSKEL; ++jj) {
                float4 c = sskl[jj];
                float s = fmaf(-sq.x, c.x, fmaf(-sq.y, c.y, fmaf(-sq.z, c.z, c.w)));
                if (s < b0)      { b1 = b0; i1 = i0; b0 = s; i0 = jj; }
                else if (s < b1) { b1 = s; i1 = jj; }
            }
            float4 c = sskl[i1];                 // knn_skele[..., 1]
            float dx = sq.x - c.x, dy = sq.y - c.y, dz = sq.z - c.z;
            v = sqrtf(dx*dx + dy*dy + dz*dz);
        }
#pragma unroll
        for (int o = 32; o > 0; o >>= 1) v += __shfl_down(v, o);
        if ((tid & 63) == 0 && tid < 128) atomicAdd(out, -0.5f * v);
    }
}

extern "C" void kernel_launch(void* const* d_in, const int* in_sizes, int n_in,
                              void* d_out, int out_size, void* d_ws, size_t ws_size,
                              hipStream_t stream) {
    const float* xyz  = (const float*)d_in[0];
    // d_in[1] = num_class (== NSKEL), compile-time constant here
    const float* skel = (const float*)d_in[2];
    float* out = (float*)d_out;

    hipMemsetAsync(out, 0, sizeof(float), stream);
    voronoi_kernel<<<BATCH * 128, 256, 0, stream>>>(xyz, skel, out);
}